// Round 1
// 532.551 us; speedup vs baseline: 1.0085x; 1.0085x over previous
//
#include <hip/hip_runtime.h>
#include <math.h>

#define NN 10000
#define DD 256
#define QQ 4096
#define CAP 128   // max neighbors kept per row; Binom(10000,0.003) tail @128 ~ 0

typedef float  fx4 __attribute__((ext_vector_type(4)));   // native vec for nontemporal builtin

// ws layout:
//   float xn[NN*DD]      normalized x rows
//   int   cnt[NN]        TRUE neighbor count per row (consumers clamp to CAP)
//   int   nbr[NN*CAP]    neighbor indices per row

// Phase 1: PURE streaming scan of adj -> neighbor lists. No emb access, no
// norm, no long-lived compute phases: the only job of this kernel is to keep
// the HBM pipe full. Non-temporal loads: adj is a 400 MB read-once stream —
// keep it from evicting the hot 10 MB emb table out of L2/L3.
__global__ __launch_bounds__(256) void scan_rows(
    const float* __restrict__ adj, int* __restrict__ cnt, int* __restrict__ nbr)
{
    const int i = blockIdx.x;
    const int t = threadIdx.x;
    __shared__ int s_cnt;
    __shared__ int s_list[CAP];
    if (t == 0) s_cnt = 0;
    __syncthreads();

    // preload all 10 float4 back-to-back for max outstanding loads
    const fx4* row = (const fx4*)(adj + (size_t)i * NN);
    fx4 r[10];
    #pragma unroll
    for (int j = 0; j < 10; ++j) {
        int k = t + j * 256;
        if (k < NN / 4) r[j] = __builtin_nontemporal_load(&row[k]);
        else            r[j] = (fx4){0.f, 0.f, 0.f, 0.f};
    }
    #pragma unroll
    for (int j = 0; j < 10; ++j) {
        fx4 v = r[j];
        int base = (t + j * 256) * 4;
        if (v.x != 0.f) { int p = atomicAdd(&s_cnt, 1); if (p < CAP) s_list[p] = base;     }
        if (v.y != 0.f) { int p = atomicAdd(&s_cnt, 1); if (p < CAP) s_list[p] = base + 1; }
        if (v.z != 0.f) { int p = atomicAdd(&s_cnt, 1); if (p < CAP) s_list[p] = base + 2; }
        if (v.w != 0.f) { int p = atomicAdd(&s_cnt, 1); if (p < CAP) s_list[p] = base + 3; }
    }
    __syncthreads();

    const int c = s_cnt;
    if (t == 0) cnt[i] = c;                  // true count (degree); clamp at use
    const int m = (c < CAP) ? c : CAP;
    if (t < m) nbr[(size_t)i * CAP + t] = s_list[t];   // m <= 128 < 256: one step
}

// Phase 2: aggregate neighbor embeddings + normalize. emb (10 MB) is hot in
// L2/L3 by the time this runs; low VGPR count -> high occupancy -> latency
// hiding for the gather chain.
__global__ __launch_bounds__(256) void gather_rows(
    const float* __restrict__ emb, const int* __restrict__ cnt,
    const int* __restrict__ nbr, float* __restrict__ xn)
{
    const int i = blockIdx.x;
    const int t = threadIdx.x;            // t in [0,256) == dim index
    __shared__ int   s_list[CAP];
    __shared__ float s_red[4];
    __shared__ float s_norm;

    const int c = cnt[i];
    const int m = (c < CAP) ? c : CAP;

    // own-row load overlaps the list load
    const float self = emb[(size_t)i * DD + t];
    if (t < m) s_list[t] = nbr[(size_t)i * CAP + t];
    __syncthreads();

    // 8 loads in flight per thread
    float a0=0.f,a1=0.f,a2=0.f,a3=0.f,a4=0.f,a5=0.f,a6=0.f,a7=0.f;
    int k = 0;
    for (; k + 8 <= m; k += 8) {
        int i0=s_list[k],   i1=s_list[k+1], i2=s_list[k+2], i3=s_list[k+3];
        int i4=s_list[k+4], i5=s_list[k+5], i6=s_list[k+6], i7=s_list[k+7];
        a0 += emb[(size_t)i0*DD + t]; a1 += emb[(size_t)i1*DD + t];
        a2 += emb[(size_t)i2*DD + t]; a3 += emb[(size_t)i3*DD + t];
        a4 += emb[(size_t)i4*DD + t]; a5 += emb[(size_t)i5*DD + t];
        a6 += emb[(size_t)i6*DD + t]; a7 += emb[(size_t)i7*DD + t];
    }
    for (; k < m; ++k) a0 += emb[(size_t)s_list[k]*DD + t];
    const float acc = ((a0+a1)+(a2+a3)) + ((a4+a5)+(a6+a7));

    const float deg = (float)c + 1e-6f;
    const float x = self + acc / deg;

    // row norm over 256 threads (4 waves of 64)
    float s = x * x;
    #pragma unroll
    for (int o = 32; o > 0; o >>= 1) s += __shfl_down(s, o, 64);
    const int lane = t & 63, wv = t >> 6;
    if (lane == 0) s_red[wv] = s;
    __syncthreads();
    if (t == 0) {
        float tot = s_red[0] + s_red[1] + s_red[2] + s_red[3];
        s_norm = fmaxf(sqrtf(tot), 1e-8f);
    }
    __syncthreads();

    xn[(size_t)i * DD + t] = x / s_norm;
}

// One wave per edge. Load both FULL CAP-sized nbr rows unconditionally and
// immediately (no dependence on cnt) to collapse the dependent-load chain;
// bound the intersection by cnt afterwards. ~91% of edges have zero common
// neighbors -> sigmoid(0)=0.5 early exit without touching xn.
__global__ __launch_bounds__(64) void edge_weights(
    const int* __restrict__ edges, const float* __restrict__ xn,
    const int* __restrict__ cnt, const int* __restrict__ nbr,
    float* __restrict__ out)
{
    const int e = blockIdx.x;
    const int lane = threadIdx.x;
    const int srcI = edges[e];
    const int dstI = edges[QQ + e];

    __shared__ int s_dst[CAP];
    __shared__ int s_com[CAP];
    __shared__ int s_ncom;

    // all four memory streams issued back-to-back:
    const int2 sA = ((const int2*)(nbr + (size_t)srcI * CAP))[lane];  // src row, 2 entries/lane
    const int2 dA = ((const int2*)(nbr + (size_t)dstI * CAP))[lane];  // dst row
    const int cs0 = cnt[srcI];
    const int cd0 = cnt[dstI];
    const int cs = (cs0 < CAP) ? cs0 : CAP;   // cnt is TRUE count now; clamp
    const int cd = (cd0 < CAP) ? cd0 : CAP;

    if (lane == 0) s_ncom = 0;
    s_dst[2 * lane]     = dA.x;
    s_dst[2 * lane + 1] = dA.y;
    __syncthreads();

    // lane owns src entries 2*lane, 2*lane+1
    {
        int k0 = 2 * lane, k1 = 2 * lane + 1;
        if (k0 < cs) {
            bool f = false;
            for (int j = 0; j < cd; ++j) { if (s_dst[j] == sA.x) { f = true; break; } }
            if (f) { int p = atomicAdd(&s_ncom, 1); s_com[p] = sA.x; }
        }
        if (k1 < cs) {
            bool f = false;
            for (int j = 0; j < cd; ++j) { if (s_dst[j] == sA.y) { f = true; break; } }
            if (f) { int p = atomicAdd(&s_ncom, 1); s_com[p] = sA.y; }
        }
    }
    __syncthreads();

    const int nc = s_ncom;
    if (nc == 0) { if (lane == 0) out[e] = 0.5f; return; }

    const float4 vs = ((const float4*)(xn + (size_t)srcI * DD))[lane];
    const float4 vd = ((const float4*)(xn + (size_t)dstI * DD))[lane];

    float w = 0.f;
    for (int q = 0; q < nc; ++q) {
        const float4 vc = ((const float4*)(xn + (size_t)s_com[q] * DD))[lane];
        float a = vs.x*vc.x + vs.y*vc.y + vs.z*vc.z + vs.w*vc.w;
        float b = vd.x*vc.x + vd.y*vc.y + vd.z*vc.z + vd.w*vc.w;
        #pragma unroll
        for (int o = 32; o > 0; o >>= 1) {
            a += __shfl_xor(a, o, 64);
            b += __shfl_xor(b, o, 64);
        }
        w += a * b;
    }
    if (lane == 0) out[e] = 1.f / (1.f + expf(-w));
}

extern "C" void kernel_launch(void* const* d_in, const int* in_sizes, int n_in,
                              void* d_out, int out_size, void* d_ws, size_t ws_size,
                              hipStream_t stream) {
    const float* emb   = (const float*)d_in[0];   // [N, D] fp32
    const float* adj   = (const float*)d_in[1];   // [N, N] fp32 (0/1)
    const int*   edges = (const int*)d_in[2];     // [2, Q] int32
    float*       out   = (float*)d_out;           // [Q] fp32

    float* xn  = (float*)d_ws;
    int*   cnt = (int*)(xn + (size_t)NN * DD);
    int*   nbr = cnt + NN;

    scan_rows<<<NN, 256, 0, stream>>>(adj, cnt, nbr);
    gather_rows<<<NN, 256, 0, stream>>>(emb, cnt, nbr, xn);
    edge_weights<<<QQ, 64, 0, stream>>>(edges, xn, cnt, nbr, out);
}